// Round 1
// baseline (226.639 us; speedup 1.0000x reference)
//
#include <hip/hip_runtime.h>

#define NODE_DIM 128
#define EDGE_DIM 16
#define MSG_DIM 128
#define HID 256
#define NB 8
#define NN 256

// ---------------------------------------------------------------------------
// K1: Ha[row,c] = sum_k h[row,k]*W1[k,c] + b1[c]        (receiver term, bias folded)
//     Hb[row,c] = sum_k h[row,k]*W1[128+k,c]            (sender term)
// row = b*N+i in [0,2048). 8 rows per block for W1 reuse out of L1/L2.
// ---------------------------------------------------------------------------
__global__ __launch_bounds__(256) void k1_precompute(
    const float* __restrict__ h, const float* __restrict__ W1,
    const float* __restrict__ b1, float* __restrict__ Ha, float* __restrict__ Hb) {
  __shared__ float sH[8 * NODE_DIM];
  const int c = threadIdx.x;
  const int r0 = blockIdx.x * 8;
  for (int idx = c; idx < 8 * NODE_DIM; idx += 256)
    sH[idx] = h[(size_t)r0 * NODE_DIM + idx];
  __syncthreads();
  float accA[8], accB[8];
#pragma unroll
  for (int r = 0; r < 8; r++) { accA[r] = 0.f; accB[r] = 0.f; }
  for (int k = 0; k < NODE_DIM; k++) {
    const float wa = W1[(size_t)k * HID + c];
    const float wb = W1[(size_t)(NODE_DIM + k) * HID + c];
#pragma unroll
    for (int r = 0; r < 8; r++) {
      const float hv = sH[r * NODE_DIM + k];
      accA[r] = fmaf(hv, wa, accA[r]);
      accB[r] = fmaf(hv, wb, accB[r]);
    }
  }
  const float bias = b1[c];
#pragma unroll
  for (int r = 0; r < 8; r++) {
    Ha[(size_t)(r0 + r) * HID + c] = accA[r] + bias;
    Hb[(size_t)(r0 + r) * HID + c] = accB[r];
  }
}

// ---------------------------------------------------------------------------
// K2: for each (b,i): aggH[b,i,c] = sum_j adj[b,i,j] *
//        relu(Ha[b,i,c] + Hb[b,j,c] + E[b,i,j,:]@W1c[:,c])
//     cnt[b,i] = sum_j adj[b,i,j]
// One block per (b,i); thread c = hidden channel. Skips adj==0 (uniform).
// ---------------------------------------------------------------------------
__global__ __launch_bounds__(256) void k2_edges(
    const float* __restrict__ Ha, const float* __restrict__ Hb,
    const float* __restrict__ E, const float* __restrict__ adj,
    const float* __restrict__ W1, float* __restrict__ aggH,
    float* __restrict__ cnt) {
  __shared__ float4 sE[NN * 4];   // 256 j * 16 edge floats = 16 KB
  __shared__ float sAdj[NN];      // 1 KB
  const int c = threadIdx.x;
  const int row = blockIdx.x;     // b*N + i
  const int b = row >> 8;

  const float4* Ebase = (const float4*)(E + (size_t)row * NN * EDGE_DIM);
  for (int idx = c; idx < NN * 4; idx += 256) sE[idx] = Ebase[idx];
  sAdj[c] = adj[(size_t)row * NN + c];
  __syncthreads();

  float w1c[16];
#pragma unroll
  for (int k = 0; k < 16; k++)
    w1c[k] = W1[(size_t)(2 * NODE_DIM + k) * HID + c];
  const float ha = Ha[(size_t)row * HID + c];
  const float* __restrict__ HbB = Hb + (size_t)b * NN * HID;

  float acc = 0.f, cn = 0.f;
  for (int j = 0; j < NN; j++) {
    const float a = sAdj[j];
    cn += a;
    if (a != 0.0f) {
      const float hb = HbB[(size_t)j * HID + c];
      const float4 e0 = sE[j * 4 + 0];
      const float4 e1 = sE[j * 4 + 1];
      const float4 e2 = sE[j * 4 + 2];
      const float4 e3 = sE[j * 4 + 3];
      // 4 independent FMA chains to hide latency
      float x0 = fmaf(e0.x, w1c[0], ha);
      float x1 = fmaf(e0.y, w1c[1], hb);
      float x2 = e0.z * w1c[2];
      float x3 = e0.w * w1c[3];
      x0 = fmaf(e1.x, w1c[4], x0);
      x1 = fmaf(e1.y, w1c[5], x1);
      x2 = fmaf(e1.z, w1c[6], x2);
      x3 = fmaf(e1.w, w1c[7], x3);
      x0 = fmaf(e2.x, w1c[8], x0);
      x1 = fmaf(e2.y, w1c[9], x1);
      x2 = fmaf(e2.z, w1c[10], x2);
      x3 = fmaf(e2.w, w1c[11], x3);
      x0 = fmaf(e3.x, w1c[12], x0);
      x1 = fmaf(e3.y, w1c[13], x1);
      x2 = fmaf(e3.z, w1c[14], x2);
      x3 = fmaf(e3.w, w1c[15], x3);
      const float x = fmaxf((x0 + x1) + (x2 + x3), 0.f);
      acc = fmaf(a, x, acc);
    }
  }
  aggH[(size_t)row * HID + c] = acc;
  if (c == 0) cnt[row] = cn;
}

// ---------------------------------------------------------------------------
// K3: per node: aggregated = aggH@W2 + cnt*b2 ; u = relu([h,agg]@U1 + c1);
//     out = u@U2 + c2.  8 rows per block for weight reuse.
// ---------------------------------------------------------------------------
__global__ __launch_bounds__(256) void k3_update(
    const float* __restrict__ h, const float* __restrict__ aggH,
    const float* __restrict__ cnt, const float* __restrict__ W2,
    const float* __restrict__ b2, const float* __restrict__ U1,
    const float* __restrict__ c1, const float* __restrict__ U2,
    const float* __restrict__ c2, float* __restrict__ out) {
  const int R = 8;
  __shared__ float sh[R * NODE_DIM];  // 4 KB
  __shared__ float sg[R * HID];       // 8 KB
  __shared__ float sa[R * MSG_DIM];   // 4 KB
  __shared__ float su[R * HID];       // 8 KB
  const int c = threadIdx.x;
  const int r0 = blockIdx.x * R;
  for (int idx = c; idx < R * NODE_DIM; idx += 256)
    sh[idx] = h[(size_t)r0 * NODE_DIM + idx];
  for (int idx = c; idx < R * HID; idx += 256)
    sg[idx] = aggH[(size_t)r0 * HID + idx];
  __syncthreads();

  // aggregated message per node: threads 0..127 own msg channel m
  if (c < MSG_DIM) {
    const int m = c;
    float accs[R];
#pragma unroll
    for (int r = 0; r < R; r++) accs[r] = cnt[r0 + r] * b2[m];
    for (int k = 0; k < HID; k++) {
      const float w = W2[(size_t)k * MSG_DIM + m];
#pragma unroll
      for (int r = 0; r < R; r++) accs[r] = fmaf(sg[r * HID + k], w, accs[r]);
    }
#pragma unroll
    for (int r = 0; r < R; r++) sa[r * MSG_DIM + m] = accs[r];
  }
  __syncthreads();

  // u_hidden: all 256 threads own hidden channel c
  {
    float accs[R];
    const float bias = c1[c];
#pragma unroll
    for (int r = 0; r < R; r++) accs[r] = bias;
    for (int k = 0; k < NODE_DIM; k++) {
      const float w = U1[(size_t)k * HID + c];
#pragma unroll
      for (int r = 0; r < R; r++) accs[r] = fmaf(sh[r * NODE_DIM + k], w, accs[r]);
    }
    for (int k = 0; k < MSG_DIM; k++) {
      const float w = U1[(size_t)(NODE_DIM + k) * HID + c];
#pragma unroll
      for (int r = 0; r < R; r++) accs[r] = fmaf(sa[r * MSG_DIM + k], w, accs[r]);
    }
#pragma unroll
    for (int r = 0; r < R; r++) su[r * HID + c] = fmaxf(accs[r], 0.f);
  }
  __syncthreads();

  // output: threads 0..127 own out channel d
  if (c < NODE_DIM) {
    const int d = c;
    float accs[R];
    const float bias = c2[d];
#pragma unroll
    for (int r = 0; r < R; r++) accs[r] = bias;
    for (int k = 0; k < HID; k++) {
      const float w = U2[(size_t)k * NODE_DIM + d];
#pragma unroll
      for (int r = 0; r < R; r++) accs[r] = fmaf(su[r * HID + k], w, accs[r]);
    }
#pragma unroll
    for (int r = 0; r < R; r++)
      out[(size_t)(r0 + r) * NODE_DIM + d] = accs[r];
  }
}

extern "C" void kernel_launch(void* const* d_in, const int* in_sizes, int n_in,
                              void* d_out, int out_size, void* d_ws, size_t ws_size,
                              hipStream_t stream) {
  const float* h   = (const float*)d_in[0];
  const float* adj = (const float*)d_in[1];
  const float* E   = (const float*)d_in[2];
  const float* W1  = (const float*)d_in[3];
  const float* b1  = (const float*)d_in[4];
  const float* W2  = (const float*)d_in[5];
  const float* b2  = (const float*)d_in[6];
  const float* U1  = (const float*)d_in[7];
  const float* c1  = (const float*)d_in[8];
  const float* U2  = (const float*)d_in[9];
  const float* c2  = (const float*)d_in[10];
  float* out = (float*)d_out;

  const size_t ROWS = (size_t)NB * NN;          // 2048
  float* ws   = (float*)d_ws;
  float* Ha   = ws;                             // 2048*256
  float* Hb   = ws + ROWS * HID;                // 2048*256
  float* aggH = ws + 2 * ROWS * HID;            // 2048*256
  float* cnt  = ws + 3 * ROWS * HID;            // 2048

  k1_precompute<<<ROWS / 8, 256, 0, stream>>>(h, W1, b1, Ha, Hb);
  k2_edges<<<ROWS, 256, 0, stream>>>(Ha, Hb, E, adj, W1, aggH, cnt);
  k3_update<<<ROWS / 8, 256, 0, stream>>>(h, aggH, cnt, W2, b2, U1, c1, U2, c2, out);
}

// Round 2
// 216.681 us; speedup vs baseline: 1.0460x; 1.0460x over previous
//
#include <hip/hip_runtime.h>

#define NODE_DIM 128
#define EDGE_DIM 16
#define MSG_DIM 128
#define HID 256
#define NB 8
#define NN 256

// ---------------------------------------------------------------------------
// K1: Ha[row,c] = sum_k h[row,k]*W1[k,c] + b1[c]   (receiver term, bias folded)
//     Hb[row,c] = sum_k h[row,k]*W1[128+k,c]       (sender term)
// R=4 rows/block -> 512 blocks (2 blocks/CU, 8 waves/CU) to hide L2 latency.
// ---------------------------------------------------------------------------
__global__ __launch_bounds__(256) void k1_precompute(
    const float* __restrict__ h, const float* __restrict__ W1,
    const float* __restrict__ b1, float* __restrict__ Ha, float* __restrict__ Hb) {
  const int R = 4;
  __shared__ float sH[R * NODE_DIM];
  const int c = threadIdx.x;
  const int r0 = blockIdx.x * R;
  for (int idx = c; idx < R * NODE_DIM; idx += 256)
    sH[idx] = h[(size_t)r0 * NODE_DIM + idx];
  __syncthreads();
  float accA[R], accB[R];
#pragma unroll
  for (int r = 0; r < R; r++) { accA[r] = 0.f; accB[r] = 0.f; }
#pragma unroll 4
  for (int k = 0; k < NODE_DIM; k++) {
    const float wa = W1[(size_t)k * HID + c];
    const float wb = W1[(size_t)(NODE_DIM + k) * HID + c];
#pragma unroll
    for (int r = 0; r < R; r++) {
      const float hv = sH[r * NODE_DIM + k];
      accA[r] = fmaf(hv, wa, accA[r]);
      accB[r] = fmaf(hv, wb, accB[r]);
    }
  }
  const float bias = b1[c];
#pragma unroll
  for (int r = 0; r < R; r++) {
    Ha[(size_t)(r0 + r) * HID + c] = accA[r] + bias;
    Hb[(size_t)(r0 + r) * HID + c] = accB[r];
  }
}

// ---------------------------------------------------------------------------
// K2: for each (b,i): aggH[b,i,c] = sum_j adj[b,i,j] *
//        relu(Ha[b,i,c] + Hb[b,j,c] + E[b,i,j,:]@W1c[:,c])
//     cnt[b,i] = sum_j adj[b,i,j]
// One block per (b,i); thread c = hidden channel. Skips adj==0 (wave-uniform).
// ---------------------------------------------------------------------------
__global__ __launch_bounds__(256) void k2_edges(
    const float* __restrict__ Ha, const float* __restrict__ Hb,
    const float* __restrict__ E, const float* __restrict__ adj,
    const float* __restrict__ W1, float* __restrict__ aggH,
    float* __restrict__ cnt) {
  __shared__ float4 sE[NN * 4];   // 256 j * 16 edge floats = 16 KB
  __shared__ float sAdj[NN];      // 1 KB
  const int c = threadIdx.x;
  const int row = blockIdx.x;     // b*N + i
  const int b = row >> 8;

  const float4* Ebase = (const float4*)(E + (size_t)row * NN * EDGE_DIM);
  for (int idx = c; idx < NN * 4; idx += 256) sE[idx] = Ebase[idx];
  sAdj[c] = adj[(size_t)row * NN + c];
  __syncthreads();

  float w1c[16];
#pragma unroll
  for (int k = 0; k < 16; k++)
    w1c[k] = W1[(size_t)(2 * NODE_DIM + k) * HID + c];
  const float ha = Ha[(size_t)row * HID + c];
  const float* __restrict__ HbB = Hb + (size_t)b * NN * HID;

  float acc = 0.f, cn = 0.f;
  for (int j = 0; j < NN; j++) {
    const float a = sAdj[j];
    cn += a;
    if (a != 0.0f) {
      const float hb = HbB[(size_t)j * HID + c];
      const float4 e0 = sE[j * 4 + 0];
      const float4 e1 = sE[j * 4 + 1];
      const float4 e2 = sE[j * 4 + 2];
      const float4 e3 = sE[j * 4 + 3];
      float x0 = fmaf(e0.x, w1c[0], ha);
      float x1 = fmaf(e0.y, w1c[1], hb);
      float x2 = e0.z * w1c[2];
      float x3 = e0.w * w1c[3];
      x0 = fmaf(e1.x, w1c[4], x0);
      x1 = fmaf(e1.y, w1c[5], x1);
      x2 = fmaf(e1.z, w1c[6], x2);
      x3 = fmaf(e1.w, w1c[7], x3);
      x0 = fmaf(e2.x, w1c[8], x0);
      x1 = fmaf(e2.y, w1c[9], x1);
      x2 = fmaf(e2.z, w1c[10], x2);
      x3 = fmaf(e2.w, w1c[11], x3);
      x0 = fmaf(e3.x, w1c[12], x0);
      x1 = fmaf(e3.y, w1c[13], x1);
      x2 = fmaf(e3.z, w1c[14], x2);
      x3 = fmaf(e3.w, w1c[15], x3);
      const float x = fmaxf((x0 + x1) + (x2 + x3), 0.f);
      acc = fmaf(a, x, acc);
    }
  }
  aggH[(size_t)row * HID + c] = acc;
  if (c == 0) cnt[row] = cn;
}

// ---------------------------------------------------------------------------
// K3: per node: aggregated = aggH@W2 + cnt*b2 ; u = relu([h,agg]@U1 + c1);
//     out = u@U2 + c2.
// R=4 rows/block -> 512 blocks. All 256 threads active in every stage:
// stages 1&3 split threads as (channel 0..127) x (row-half 0..1).
// ---------------------------------------------------------------------------
__global__ __launch_bounds__(256) void k3_update(
    const float* __restrict__ h, const float* __restrict__ aggH,
    const float* __restrict__ cnt, const float* __restrict__ W2,
    const float* __restrict__ b2, const float* __restrict__ U1,
    const float* __restrict__ c1, const float* __restrict__ U2,
    const float* __restrict__ c2, float* __restrict__ out) {
  const int R = 4;
  __shared__ float sh[R * NODE_DIM];  // 2 KB
  __shared__ float sg[R * HID];       // 4 KB
  __shared__ float sa[R * MSG_DIM];   // 2 KB
  __shared__ float su[R * HID];       // 4 KB
  const int c = threadIdx.x;
  const int r0 = blockIdx.x * R;
  for (int idx = c; idx < R * NODE_DIM; idx += 256)
    sh[idx] = h[(size_t)r0 * NODE_DIM + idx];
  for (int idx = c; idx < R * HID; idx += 256)
    sg[idx] = aggH[(size_t)r0 * HID + idx];
  __syncthreads();

  // stage 1: aggregated = aggH@W2 + cnt*b2.
  // thread -> (m = c&127, rows {rh*2, rh*2+1} where rh = c>>7)
  {
    const int m = c & 127;
    const int rb = (c >> 7) * 2;
    float a0 = cnt[r0 + rb + 0] * b2[m];
    float a1 = cnt[r0 + rb + 1] * b2[m];
#pragma unroll 4
    for (int k = 0; k < HID; k++) {
      const float w = W2[(size_t)k * MSG_DIM + m];
      a0 = fmaf(sg[(rb + 0) * HID + k], w, a0);
      a1 = fmaf(sg[(rb + 1) * HID + k], w, a1);
    }
    sa[(rb + 0) * MSG_DIM + m] = a0;
    sa[(rb + 1) * MSG_DIM + m] = a1;
  }
  __syncthreads();

  // stage 2: u = relu([h, agg]@U1 + c1). all 256 threads own hidden ch c.
  {
    float accs[R];
    const float bias = c1[c];
#pragma unroll
    for (int r = 0; r < R; r++) accs[r] = bias;
#pragma unroll 4
    for (int k = 0; k < NODE_DIM; k++) {
      const float w = U1[(size_t)k * HID + c];
#pragma unroll
      for (int r = 0; r < R; r++) accs[r] = fmaf(sh[r * NODE_DIM + k], w, accs[r]);
    }
#pragma unroll 4
    for (int k = 0; k < MSG_DIM; k++) {
      const float w = U1[(size_t)(NODE_DIM + k) * HID + c];
#pragma unroll
      for (int r = 0; r < R; r++) accs[r] = fmaf(sa[r * MSG_DIM + k], w, accs[r]);
    }
#pragma unroll
    for (int r = 0; r < R; r++) su[r * HID + c] = fmaxf(accs[r], 0.f);
  }
  __syncthreads();

  // stage 3: out = u@U2 + c2. thread -> (d = c&127, 2 rows)
  {
    const int d = c & 127;
    const int rb = (c >> 7) * 2;
    float a0 = c2[d];
    float a1 = a0;
#pragma unroll 4
    for (int k = 0; k < HID; k++) {
      const float w = U2[(size_t)k * NODE_DIM + d];
      a0 = fmaf(su[(rb + 0) * HID + k], w, a0);
      a1 = fmaf(su[(rb + 1) * HID + k], w, a1);
    }
    out[(size_t)(r0 + rb + 0) * NODE_DIM + d] = a0;
    out[(size_t)(r0 + rb + 1) * NODE_DIM + d] = a1;
  }
}

extern "C" void kernel_launch(void* const* d_in, const int* in_sizes, int n_in,
                              void* d_out, int out_size, void* d_ws, size_t ws_size,
                              hipStream_t stream) {
  const float* h   = (const float*)d_in[0];
  const float* adj = (const float*)d_in[1];
  const float* E   = (const float*)d_in[2];
  const float* W1  = (const float*)d_in[3];
  const float* b1  = (const float*)d_in[4];
  const float* W2  = (const float*)d_in[5];
  const float* b2  = (const float*)d_in[6];
  const float* U1  = (const float*)d_in[7];
  const float* c1  = (const float*)d_in[8];
  const float* U2  = (const float*)d_in[9];
  const float* c2  = (const float*)d_in[10];
  float* out = (float*)d_out;

  const size_t ROWS = (size_t)NB * NN;          // 2048
  float* ws   = (float*)d_ws;
  float* Ha   = ws;                             // 2048*256
  float* Hb   = ws + ROWS * HID;                // 2048*256
  float* aggH = ws + 2 * ROWS * HID;            // 2048*256
  float* cnt  = ws + 3 * ROWS * HID;            // 2048

  k1_precompute<<<ROWS / 4, 256, 0, stream>>>(h, W1, b1, Ha, Hb);
  k2_edges<<<ROWS, 256, 0, stream>>>(Ha, Hb, E, adj, W1, aggH, cnt);
  k3_update<<<ROWS / 4, 256, 0, stream>>>(h, aggH, cnt, W2, b2, U1, c1, U2, c2, out);
}

// Round 3
// 196.658 us; speedup vs baseline: 1.1525x; 1.1018x over previous
//
#include <hip/hip_runtime.h>

#define NODE_DIM 128
#define EDGE_DIM 16
#define MSG_DIM 128
#define HID 256
#define NB 8
#define NN 256

// Async bulk copy global->LDS, 16B/lane. lbase must be wave-uniform (HW adds
// lane*16); gbase contiguous. bytes must be a multiple of 4096 (4 waves x 1KB).
__device__ __forceinline__ void cp_glds_16(const void* gbase, void* lbase,
                                           int bytes, int tid) {
  const int lane = tid & 63;
  const int wave = tid >> 6;  // 4 waves / block
  for (int off = wave * 1024; off < bytes; off += 4096) {
    const char* g = (const char*)gbase + off + lane * 16;
    char* l = (char*)lbase + off;  // wave-uniform LDS base
    __builtin_amdgcn_global_load_lds(
        (const __attribute__((address_space(1))) void*)g,
        (__attribute__((address_space(3))) void*)l, 16, 0, 0);
  }
}

// ---------------------------------------------------------------------------
// K1: Ha[row,c] = sum_k h[row,k]*W1[k,c] + b1[c]; Hb[row,c] = sum h*W1[128+k,c]
// W1 rows 0..255 streamed through a 32KB LDS tile (32 k-rows x 256 c).
// R=4 rows/block -> 512 blocks.
// ---------------------------------------------------------------------------
__global__ __launch_bounds__(256) void k1_precompute(
    const float* __restrict__ h, const float* __restrict__ W1,
    const float* __restrict__ b1, float* __restrict__ Ha, float* __restrict__ Hb) {
  const int R = 4;
  __shared__ __align__(16) float sH[R * NODE_DIM];  // 2 KB
  __shared__ __align__(16) float swt[32 * HID];     // 32 KB weight k-tile
  const int c = threadIdx.x;
  const int r0 = blockIdx.x * R;
  for (int idx = c; idx < R * NODE_DIM; idx += 256)
    sH[idx] = h[(size_t)r0 * NODE_DIM + idx];

  float accA[R] = {0.f, 0.f, 0.f, 0.f};
  float accB[R] = {0.f, 0.f, 0.f, 0.f};
  // tiles 0..3: W1 rows 0..127 -> accA
  for (int t = 0; t < 4; t++) {
    cp_glds_16(W1 + (size_t)t * 32 * HID, swt, 32 * HID * 4, c);
    __syncthreads();
    const int kb = t * 32;
#pragma unroll 4
    for (int k = 0; k < 32; k++) {
      const float w = swt[k * HID + c];
#pragma unroll
      for (int r = 0; r < R; r++)
        accA[r] = fmaf(sH[r * NODE_DIM + kb + k], w, accA[r]);
    }
    __syncthreads();
  }
  // tiles 4..7: W1 rows 128..255 -> accB
  for (int t = 4; t < 8; t++) {
    cp_glds_16(W1 + (size_t)t * 32 * HID, swt, 32 * HID * 4, c);
    __syncthreads();
    const int kb = t * 32 - 128;
#pragma unroll 4
    for (int k = 0; k < 32; k++) {
      const float w = swt[k * HID + c];
#pragma unroll
      for (int r = 0; r < R; r++)
        accB[r] = fmaf(sH[r * NODE_DIM + kb + k], w, accB[r]);
    }
    __syncthreads();
  }
  const float bias = b1[c];
#pragma unroll
  for (int r = 0; r < R; r++) {
    Ha[(size_t)(r0 + r) * HID + c] = accA[r] + bias;
    Hb[(size_t)(r0 + r) * HID + c] = accB[r];
  }
}

// ---------------------------------------------------------------------------
// K2: aggH[b,i,c] = sum_j adj * relu(Ha[b,i,c] + Hb[b,j,c] + E[b,i,j,:]@W1c[:,c])
// cnt[b,i] = sum_j adj. One block per (b,i). (Unchanged from R1.)
// ---------------------------------------------------------------------------
__global__ __launch_bounds__(256) void k2_edges(
    const float* __restrict__ Ha, const float* __restrict__ Hb,
    const float* __restrict__ E, const float* __restrict__ adj,
    const float* __restrict__ W1, float* __restrict__ aggH,
    float* __restrict__ cnt) {
  __shared__ float4 sE[NN * 4];  // 16 KB
  __shared__ float sAdj[NN];     // 1 KB
  const int c = threadIdx.x;
  const int row = blockIdx.x;  // b*N + i
  const int b = row >> 8;

  const float4* Ebase = (const float4*)(E + (size_t)row * NN * EDGE_DIM);
  for (int idx = c; idx < NN * 4; idx += 256) sE[idx] = Ebase[idx];
  sAdj[c] = adj[(size_t)row * NN + c];
  __syncthreads();

  float w1c[16];
#pragma unroll
  for (int k = 0; k < 16; k++)
    w1c[k] = W1[(size_t)(2 * NODE_DIM + k) * HID + c];
  const float ha = Ha[(size_t)row * HID + c];
  const float* __restrict__ HbB = Hb + (size_t)b * NN * HID;

  float acc = 0.f, cn = 0.f;
  for (int j = 0; j < NN; j++) {
    const float a = sAdj[j];
    cn += a;
    if (a != 0.0f) {
      const float hb = HbB[(size_t)j * HID + c];
      const float4 e0 = sE[j * 4 + 0];
      const float4 e1 = sE[j * 4 + 1];
      const float4 e2 = sE[j * 4 + 2];
      const float4 e3 = sE[j * 4 + 3];
      float x0 = fmaf(e0.x, w1c[0], ha);
      float x1 = fmaf(e0.y, w1c[1], hb);
      float x2 = e0.z * w1c[2];
      float x3 = e0.w * w1c[3];
      x0 = fmaf(e1.x, w1c[4], x0);
      x1 = fmaf(e1.y, w1c[5], x1);
      x2 = fmaf(e1.z, w1c[6], x2);
      x3 = fmaf(e1.w, w1c[7], x3);
      x0 = fmaf(e2.x, w1c[8], x0);
      x1 = fmaf(e2.y, w1c[9], x1);
      x2 = fmaf(e2.z, w1c[10], x2);
      x3 = fmaf(e2.w, w1c[11], x3);
      x0 = fmaf(e3.x, w1c[12], x0);
      x1 = fmaf(e3.y, w1c[13], x1);
      x2 = fmaf(e3.z, w1c[14], x2);
      x3 = fmaf(e3.w, w1c[15], x3);
      const float x = fmaxf((x0 + x1) + (x2 + x3), 0.f);
      acc = fmaf(a, x, acc);
    }
  }
  aggH[(size_t)row * HID + c] = acc;
  if (c == 0) cnt[row] = cn;
}

// ---------------------------------------------------------------------------
// K3: agg = aggH@W2 + cnt*b2; u = relu([h,agg]@U1 + c1); out = u@U2 + c2.
// All weights streamed through one 32KB LDS tile. R=4 rows -> 512 blocks.
// ---------------------------------------------------------------------------
__global__ __launch_bounds__(256) void k3_update(
    const float* __restrict__ h, const float* __restrict__ aggH,
    const float* __restrict__ cnt, const float* __restrict__ W2,
    const float* __restrict__ b2, const float* __restrict__ U1,
    const float* __restrict__ c1, const float* __restrict__ U2,
    const float* __restrict__ c2, float* __restrict__ out) {
  const int R = 4;
  __shared__ __align__(16) float sh[R * NODE_DIM];  // 2 KB
  __shared__ __align__(16) float sg[R * HID];       // 4 KB
  __shared__ __align__(16) float sa[R * MSG_DIM];   // 2 KB
  __shared__ __align__(16) float su[R * HID];       // 4 KB
  __shared__ __align__(16) float swt[32 * HID];     // 32 KB weight tile
  const int c = threadIdx.x;
  const int r0 = blockIdx.x * R;
  for (int idx = c; idx < R * NODE_DIM; idx += 256)
    sh[idx] = h[(size_t)r0 * NODE_DIM + idx];
  for (int idx = c; idx < R * HID; idx += 256)
    sg[idx] = aggH[(size_t)r0 * HID + idx];

  // ---- stage 1: agg = aggH@W2 + cnt*b2. thread -> (m=c&127, 2 rows) ----
  {
    const int m = c & 127;
    const int rb = (c >> 7) * 2;
    float a0 = cnt[r0 + rb + 0] * b2[m];
    float a1 = cnt[r0 + rb + 1] * b2[m];
    for (int t = 0; t < 4; t++) {  // 64 k-rows x 128 m = 32 KB per tile
      cp_glds_16(W2 + (size_t)t * 64 * MSG_DIM, swt, 64 * MSG_DIM * 4, c);
      __syncthreads();
      const int kb = t * 64;
#pragma unroll 4
      for (int k = 0; k < 64; k++) {
        const float w = swt[k * MSG_DIM + m];
        a0 = fmaf(sg[(rb + 0) * HID + kb + k], w, a0);
        a1 = fmaf(sg[(rb + 1) * HID + kb + k], w, a1);
      }
      __syncthreads();
    }
    sa[(rb + 0) * MSG_DIM + m] = a0;
    sa[(rb + 1) * MSG_DIM + m] = a1;
  }
  __syncthreads();

  // ---- stage 2: u = relu([h, agg]@U1 + c1). thread -> hidden ch c, 4 rows --
  {
    float accs[R];
    const float bias = c1[c];
#pragma unroll
    for (int r = 0; r < R; r++) accs[r] = bias;
    // tiles 0..3: U1 rows 0..127, input sh
    for (int t = 0; t < 4; t++) {  // 32 k-rows x 256 c = 32 KB
      cp_glds_16(U1 + (size_t)t * 32 * HID, swt, 32 * HID * 4, c);
      __syncthreads();
      const int kb = t * 32;
#pragma unroll 4
      for (int k = 0; k < 32; k++) {
        const float w = swt[k * HID + c];
#pragma unroll
        for (int r = 0; r < R; r++)
          accs[r] = fmaf(sh[r * NODE_DIM + kb + k], w, accs[r]);
      }
      __syncthreads();
    }
    // tiles 4..7: U1 rows 128..255, input sa
    for (int t = 4; t < 8; t++) {
      cp_glds_16(U1 + (size_t)t * 32 * HID, swt, 32 * HID * 4, c);
      __syncthreads();
      const int kb = t * 32 - 128;
#pragma unroll 4
      for (int k = 0; k < 32; k++) {
        const float w = swt[k * HID + c];
#pragma unroll
        for (int r = 0; r < R; r++)
          accs[r] = fmaf(sa[r * MSG_DIM + kb + k], w, accs[r]);
      }
      __syncthreads();
    }
#pragma unroll
    for (int r = 0; r < R; r++) su[r * HID + c] = fmaxf(accs[r], 0.f);
  }
  __syncthreads();

  // ---- stage 3: out = u@U2 + c2. thread -> (d=c&127, 2 rows) ----
  {
    const int d = c & 127;
    const int rb = (c >> 7) * 2;
    float a0 = c2[d];
    float a1 = a0;
    for (int t = 0; t < 4; t++) {  // 64 k-rows x 128 d = 32 KB
      cp_glds_16(U2 + (size_t)t * 64 * NODE_DIM, swt, 64 * NODE_DIM * 4, c);
      __syncthreads();
      const int kb = t * 64;
#pragma unroll 4
      for (int k = 0; k < 64; k++) {
        const float w = swt[k * NODE_DIM + d];
        a0 = fmaf(su[(rb + 0) * HID + kb + k], w, a0);
        a1 = fmaf(su[(rb + 1) * HID + kb + k], w, a1);
      }
      __syncthreads();
    }
    out[(size_t)(r0 + rb + 0) * NODE_DIM + d] = a0;
    out[(size_t)(r0 + rb + 1) * NODE_DIM + d] = a1;
  }
}

extern "C" void kernel_launch(void* const* d_in, const int* in_sizes, int n_in,
                              void* d_out, int out_size, void* d_ws, size_t ws_size,
                              hipStream_t stream) {
  const float* h   = (const float*)d_in[0];
  const float* adj = (const float*)d_in[1];
  const float* E   = (const float*)d_in[2];
  const float* W1  = (const float*)d_in[3];
  const float* b1  = (const float*)d_in[4];
  const float* W2  = (const float*)d_in[5];
  const float* b2  = (const float*)d_in[6];
  const float* U1  = (const float*)d_in[7];
  const float* c1  = (const float*)d_in[8];
  const float* U2  = (const float*)d_in[9];
  const float* c2  = (const float*)d_in[10];
  float* out = (float*)d_out;

  const size_t ROWS = (size_t)NB * NN;  // 2048
  float* ws   = (float*)d_ws;
  float* Ha   = ws;                      // 2048*256
  float* Hb   = ws + ROWS * HID;         // 2048*256
  float* aggH = ws + 2 * ROWS * HID;     // 2048*256
  float* cnt  = ws + 3 * ROWS * HID;     // 2048

  k1_precompute<<<ROWS / 4, 256, 0, stream>>>(h, W1, b1, Ha, Hb);
  k2_edges<<<ROWS, 256, 0, stream>>>(Ha, Hb, E, adj, W1, aggH, cnt);
  k3_update<<<ROWS / 4, 256, 0, stream>>>(h, aggH, cnt, W2, b2, U1, c1, U2, c2, out);
}

// Round 5
// 167.236 us; speedup vs baseline: 1.3552x; 1.1759x over previous
//
#include <hip/hip_runtime.h>

#define NODE_DIM 128
#define EDGE_DIM 16
#define MSG_DIM 128
#define HID 256
#define NB 8
#define NN 256

typedef short bf16x8 __attribute__((ext_vector_type(8)));
typedef float f32x4 __attribute__((ext_vector_type(4)));

// Async bulk copy global->LDS, 16B/lane. lbase must be wave-uniform (HW adds
// lane*16); gbase contiguous. bytes must be a multiple of 4096 (4 waves x 1KB).
__device__ __forceinline__ void cp_glds_16(const void* gbase, void* lbase,
                                           int bytes, int tid) {
  const int lane = tid & 63;
  const int wave = tid >> 6;  // 4 waves / block
  for (int off = wave * 1024; off < bytes; off += 4096) {
    const char* g = (const char*)gbase + off + lane * 16;
    char* l = (char*)lbase + off;  // wave-uniform LDS base
    __builtin_amdgcn_global_load_lds(
        (const __attribute__((address_space(1))) void*)g,
        (__attribute__((address_space(3))) void*)l, 16, 0, 0);
  }
}

__device__ __forceinline__ unsigned short f2bf(float f) {
  unsigned u = __float_as_uint(f);
  return (unsigned short)((u + 0x7FFF + ((u >> 16) & 1)) >> 16);
}
// pack two floats as bf16 pair (lo in low 16, hi in high 16), RNE rounding.
__device__ __forceinline__ unsigned pack_bf2(float lo, float hi) {
  unsigned a = __float_as_uint(lo), b = __float_as_uint(hi);
  a = (a + 0x7FFF + ((a >> 16) & 1)) >> 16;            // rounded low half
  b = (b + 0x7FFF + ((b >> 16) & 1)) & 0xFFFF0000u;    // rounded high half in place
  return a | b;
}

// ---------------------------------------------------------------------------
// K1: Ha[row,c] = sum_k h[row,k]*W1[k,c] + b1[c]; Hb[row,c] = sum h*W1[128+k,c]
// ---------------------------------------------------------------------------
__global__ __launch_bounds__(256) void k1_precompute(
    const float* __restrict__ h, const float* __restrict__ W1,
    const float* __restrict__ b1, float* __restrict__ Ha, float* __restrict__ Hb) {
  const int R = 4;
  __shared__ __align__(16) float sH[R * NODE_DIM];
  __shared__ __align__(16) float swt[32 * HID];
  const int c = threadIdx.x;
  const int r0 = blockIdx.x * R;
  for (int idx = c; idx < R * NODE_DIM; idx += 256)
    sH[idx] = h[(size_t)r0 * NODE_DIM + idx];

  float accA[R] = {0.f, 0.f, 0.f, 0.f};
  float accB[R] = {0.f, 0.f, 0.f, 0.f};
  for (int t = 0; t < 4; t++) {
    cp_glds_16(W1 + (size_t)t * 32 * HID, swt, 32 * HID * 4, c);
    __syncthreads();
    const int kb = t * 32;
#pragma unroll 4
    for (int k = 0; k < 32; k++) {
      const float w = swt[k * HID + c];
#pragma unroll
      for (int r = 0; r < R; r++)
        accA[r] = fmaf(sH[r * NODE_DIM + kb + k], w, accA[r]);
    }
    __syncthreads();
  }
  for (int t = 4; t < 8; t++) {
    cp_glds_16(W1 + (size_t)t * 32 * HID, swt, 32 * HID * 4, c);
    __syncthreads();
    const int kb = t * 32 - 128;
#pragma unroll 4
    for (int k = 0; k < 32; k++) {
      const float w = swt[k * HID + c];
#pragma unroll
      for (int r = 0; r < R; r++)
        accB[r] = fmaf(sH[r * NODE_DIM + kb + k], w, accB[r]);
    }
    __syncthreads();
  }
  const float bias = b1[c];
#pragma unroll
  for (int r = 0; r < R; r++) {
    Ha[(size_t)(r0 + r) * HID + c] = accA[r] + bias;
    Hb[(size_t)(r0 + r) * HID + c] = accB[r];
  }
}

// ---------------------------------------------------------------------------
// K2 (MFMA): per block: 4 node-rows i (r0..r0+3 of the same batch b).
//   aggH[i,c] = sum_j adj[i,j] * relu( Ha[i,c] + Hb[j,c] + E[i,j,:]@W1c[:,c] )
// E@W1c via mfma_f32_16x16x32_bf16 (K padded 16->32 with zeroed B-frags).
//   A layout: m=lane&15, k=quad*8+j   (quads>=2 read junk, nulled by B=0)
//   C/D     : col=lane&15, row=quad*4+reg
// ---------------------------------------------------------------------------
__global__ __launch_bounds__(256) void k2_mfma(
    const float* __restrict__ Ha, const float* __restrict__ Hb,
    const float* __restrict__ E, const float* __restrict__ adj,
    const float* __restrict__ W1, float* __restrict__ aggH,
    float* __restrict__ cnt) {
  __shared__ __align__(16) unsigned sEbU[4 * NN * 12];  // 48 KB bf16 E, row stride 24
  __shared__ __align__(16) float sHb[16 * HID];         // 16 KB Hb j-tile
  __shared__ __align__(16) float sAdj[4 * NN];          // 4 KB
  const int tid = threadIdx.x;
  const int lane = tid & 63;
  const int wave = tid >> 6;
  const int n = lane & 15;
  const int quad = lane >> 4;
  const int c0 = wave * 64;
  const int r0 = blockIdx.x * 4;
  const int b = r0 >> 8;

  // ---- stage E (fp32 -> bf16, row stride 12 u32) and adj ----
  const float4* Eb4 = (const float4*)(E + (size_t)r0 * NN * EDGE_DIM);
  for (int q = tid; q < 4 * NN * 4; q += 256) {
    const float4 v = Eb4[q];
    const int row = q >> 2;
    const int ku = (q & 3) << 1;
    sEbU[row * 12 + ku] = pack_bf2(v.x, v.y);
    sEbU[row * 12 + ku + 1] = pack_bf2(v.z, v.w);
  }
  for (int idx = tid; idx < 4 * NN; idx += 256)
    sAdj[idx] = adj[(size_t)r0 * NN + idx];

  // ---- B fragments: W1c[k, c0+ct*16+n], k=quad*8+jj (zero for k>=16) ----
  union { bf16x8 v; unsigned short s[8]; } bfrag[4];
#pragma unroll
  for (int ct = 0; ct < 4; ct++) {
#pragma unroll
    for (int jj = 0; jj < 8; jj++) {
      float w = 0.f;
      if (quad < 2)
        w = W1[(size_t)(2 * NODE_DIM + quad * 8 + jj) * HID + c0 + ct * 16 + n];
      bfrag[ct].s[jj] = (short)f2bf(w);
    }
  }
  // ---- Ha seeds ----
  float hav[4][4];
#pragma unroll
  for (int i = 0; i < 4; i++)
#pragma unroll
    for (int ct = 0; ct < 4; ct++)
      hav[i][ct] = Ha[(size_t)(r0 + i) * HID + c0 + ct * 16 + n];

  __syncthreads();

  // ---- cnt: wave w reduces sAdj row w ----
  {
    float s = sAdj[wave * NN + lane] + sAdj[wave * NN + lane + 64] +
              sAdj[wave * NN + lane + 128] + sAdj[wave * NN + lane + 192];
    for (int d = 32; d; d >>= 1) s += __shfl_xor(s, d);
    if (lane == 0) cnt[r0 + wave] = s;
  }

  float outp[4][4];
#pragma unroll
  for (int i = 0; i < 4; i++)
#pragma unroll
    for (int ct = 0; ct < 4; ct++) outp[i][ct] = 0.f;

  // ---- main loop over j-tiles of 16 ----
  for (int jt = 0; jt < 16; jt++) {
    const int j0 = jt * 16;
    cp_glds_16(Hb + ((size_t)(b * NN) + j0) * HID, sHb, 16 * HID * 4, tid);
    __syncthreads();
#pragma unroll
    for (int i = 0; i < 4; i++) {
      const bf16x8 af = *(const bf16x8*)((const char*)sEbU +
          (size_t)(i * NN + j0 + n) * 48 + (quad & 1) * 16);
      const float4 adjv = *(const float4*)(sAdj + i * NN + j0 + quad * 4);
#pragma unroll
      for (int ct = 0; ct < 4; ct++) {
        f32x4 cseed;
        cseed[0] = hav[i][ct]; cseed[1] = hav[i][ct];
        cseed[2] = hav[i][ct]; cseed[3] = hav[i][ct];
        f32x4 acc = __builtin_amdgcn_mfma_f32_16x16x32_bf16(
            af, bfrag[ct].v, cseed, 0, 0, 0);
        const int colb = c0 + ct * 16 + n;
#pragma unroll
        for (int r = 0; r < 4; r++) {
          const float hb = sHb[(quad * 4 + r) * HID + colb];
          const float x = fmaxf(acc[r] + hb, 0.f);
          const float a = (r == 0) ? adjv.x : (r == 1) ? adjv.y
                        : (r == 2) ? adjv.z : adjv.w;
          outp[i][ct] = fmaf(a, x, outp[i][ct]);
        }
      }
    }
    __syncthreads();
  }

  // ---- reduce across quads, store ----
#pragma unroll
  for (int i = 0; i < 4; i++)
#pragma unroll
    for (int ct = 0; ct < 4; ct++) {
      float v = outp[i][ct];
      v += __shfl_xor(v, 16);
      v += __shfl_xor(v, 32);
      if (quad == 0)
        aggH[(size_t)(r0 + i) * HID + c0 + ct * 16 + n] = v;
    }
}

// ---------------------------------------------------------------------------
// K3: agg = aggH@W2 + cnt*b2; u = relu([h,agg]@U1 + c1); out = u@U2 + c2.
// ---------------------------------------------------------------------------
__global__ __launch_bounds__(256) void k3_update(
    const float* __restrict__ h, const float* __restrict__ aggH,
    const float* __restrict__ cnt, const float* __restrict__ W2,
    const float* __restrict__ b2, const float* __restrict__ U1,
    const float* __restrict__ c1, const float* __restrict__ U2,
    const float* __restrict__ c2, float* __restrict__ out) {
  const int R = 4;
  __shared__ __align__(16) float sh[R * NODE_DIM];
  __shared__ __align__(16) float sg[R * HID];
  __shared__ __align__(16) float sa[R * MSG_DIM];
  __shared__ __align__(16) float su[R * HID];
  __shared__ __align__(16) float swt[32 * HID];
  const int c = threadIdx.x;
  const int r0 = blockIdx.x * R;
  for (int idx = c; idx < R * NODE_DIM; idx += 256)
    sh[idx] = h[(size_t)r0 * NODE_DIM + idx];
  for (int idx = c; idx < R * HID; idx += 256)
    sg[idx] = aggH[(size_t)r0 * HID + idx];

  {
    const int m = c & 127;
    const int rb = (c >> 7) * 2;
    float a0 = cnt[r0 + rb + 0] * b2[m];
    float a1 = cnt[r0 + rb + 1] * b2[m];
    for (int t = 0; t < 4; t++) {
      cp_glds_16(W2 + (size_t)t * 64 * MSG_DIM, swt, 64 * MSG_DIM * 4, c);
      __syncthreads();
      const int kb = t * 64;
#pragma unroll 4
      for (int k = 0; k < 64; k++) {
        const float w = swt[k * MSG_DIM + m];
        a0 = fmaf(sg[(rb + 0) * HID + kb + k], w, a0);
        a1 = fmaf(sg[(rb + 1) * HID + kb + k], w, a1);
      }
      __syncthreads();
    }
    sa[(rb + 0) * MSG_DIM + m] = a0;
    sa[(rb + 1) * MSG_DIM + m] = a1;
  }
  __syncthreads();

  {
    float accs[R];
    const float bias = c1[c];
#pragma unroll
    for (int r = 0; r < R; r++) accs[r] = bias;
    for (int t = 0; t < 4; t++) {
      cp_glds_16(U1 + (size_t)t * 32 * HID, swt, 32 * HID * 4, c);
      __syncthreads();
      const int kb = t * 32;
#pragma unroll 4
      for (int k = 0; k < 32; k++) {
        const float w = swt[k * HID + c];
#pragma unroll
        for (int r = 0; r < R; r++)
          accs[r] = fmaf(sh[r * NODE_DIM + kb + k], w, accs[r]);
      }
      __syncthreads();
    }
    for (int t = 4; t < 8; t++) {
      cp_glds_16(U1 + (size_t)t * 32 * HID, swt, 32 * HID * 4, c);
      __syncthreads();
      const int kb = t * 32 - 128;
#pragma unroll 4
      for (int k = 0; k < 32; k++) {
        const float w = swt[k * HID + c];
#pragma unroll
        for (int r = 0; r < R; r++)
          accs[r] = fmaf(sa[r * MSG_DIM + kb + k], w, accs[r]);
      }
      __syncthreads();
    }
#pragma unroll
    for (int r = 0; r < R; r++) su[r * HID + c] = fmaxf(accs[r], 0.f);
  }
  __syncthreads();

  {
    const int d = c & 127;
    const int rb = (c >> 7) * 2;
    float a0 = c2[d];
    float a1 = a0;
    for (int t = 0; t < 4; t++) {
      cp_glds_16(U2 + (size_t)t * 64 * NODE_DIM, swt, 64 * NODE_DIM * 4, c);
      __syncthreads();
      const int kb = t * 64;
#pragma unroll 4
      for (int k = 0; k < 64; k++) {
        const float w = swt[k * NODE_DIM + d];
        a0 = fmaf(su[(rb + 0) * HID + kb + k], w, a0);
        a1 = fmaf(su[(rb + 1) * HID + kb + k], w, a1);
      }
      __syncthreads();
    }
    out[(size_t)(r0 + rb + 0) * NODE_DIM + d] = a0;
    out[(size_t)(r0 + rb + 1) * NODE_DIM + d] = a1;
  }
}

extern "C" void kernel_launch(void* const* d_in, const int* in_sizes, int n_in,
                              void* d_out, int out_size, void* d_ws, size_t ws_size,
                              hipStream_t stream) {
  const float* h   = (const float*)d_in[0];
  const float* adj = (const float*)d_in[1];
  const float* E   = (const float*)d_in[2];
  const float* W1  = (const float*)d_in[3];
  const float* b1  = (const float*)d_in[4];
  const float* W2  = (const float*)d_in[5];
  const float* b2  = (const float*)d_in[6];
  const float* U1  = (const float*)d_in[7];
  const float* c1  = (const float*)d_in[8];
  const float* U2  = (const float*)d_in[9];
  const float* c2  = (const float*)d_in[10];
  float* out = (float*)d_out;

  const size_t ROWS = (size_t)NB * NN;  // 2048
  float* ws   = (float*)d_ws;
  float* Ha   = ws;                      // 2048*256
  float* Hb   = ws + ROWS * HID;         // 2048*256
  float* aggH = ws + 2 * ROWS * HID;     // 2048*256
  float* cnt  = ws + 3 * ROWS * HID;     // 2048

  k1_precompute<<<ROWS / 4, 256, 0, stream>>>(h, W1, b1, Ha, Hb);
  k2_mfma<<<ROWS / 4, 256, 0, stream>>>(Ha, Hb, E, adj, W1, aggH, cnt);
  k3_update<<<ROWS / 4, 256, 0, stream>>>(h, aggH, cnt, W2, b2, U1, c1, U2, c2, out);
}

// Round 6
// 157.316 us; speedup vs baseline: 1.4407x; 1.0631x over previous
//
#include <hip/hip_runtime.h>

#define NODE_DIM 128
#define EDGE_DIM 16
#define MSG_DIM 128
#define HID 256
#define NB 8
#define NN 256

typedef short bf16x8 __attribute__((ext_vector_type(8)));
typedef float f32x4 __attribute__((ext_vector_type(4)));

// Async bulk copy global->LDS, 16B/lane (k2 only). lbase wave-uniform.
__device__ __forceinline__ void cp_glds_16(const void* gbase, void* lbase,
                                           int bytes, int tid) {
  const int lane = tid & 63;
  const int wave = tid >> 6;
  for (int off = wave * 1024; off < bytes; off += 4096) {
    const char* g = (const char*)gbase + off + lane * 16;
    char* l = (char*)lbase + off;
    __builtin_amdgcn_global_load_lds(
        (const __attribute__((address_space(1))) void*)g,
        (__attribute__((address_space(3))) void*)l, 16, 0, 0);
  }
}

__device__ __forceinline__ unsigned short f2bf(float f) {
  unsigned u = __float_as_uint(f);
  return (unsigned short)((u + 0x7FFF + ((u >> 16) & 1)) >> 16);
}
__device__ __forceinline__ unsigned pack_bf2(float lo, float hi) {
  unsigned a = __float_as_uint(lo), b = __float_as_uint(hi);
  a = (a + 0x7FFF + ((a >> 16) & 1)) >> 16;
  b = (b + 0x7FFF + ((b >> 16) & 1)) & 0xFFFF0000u;
  return a | b;
}

union BF8 { bf16x8 v; unsigned u[4]; unsigned short s[8]; };

__device__ __forceinline__ BF8 make_bf8(float4 a, float4 b) {
  BF8 r;
  r.u[0] = pack_bf2(a.x, a.y); r.u[1] = pack_bf2(a.z, a.w);
  r.u[2] = pack_bf2(b.x, b.y); r.u[3] = pack_bf2(b.z, b.w);
  return r;
}

// Load B-fragment: W[(koff + ks*32 + quad*8 + j)*ldw + ncol], j=0..7, as bf16.
__device__ __forceinline__ BF8 load_bfrag(const float* __restrict__ W, int row0,
                                          int ldw, int ncol) {
  BF8 r;
#pragma unroll
  for (int j = 0; j < 8; j++)
    r.s[j] = f2bf(W[(size_t)(row0 + j) * ldw + ncol]);
  return r;
}

// ---------------------------------------------------------------------------
// K1 (MFMA, no barriers): [Ha | Hb] = h @ W1[0:256,:] (+ b1 for Ha).
// Block = 16 rows, 4 waves; wave w owns n-tiles w*8..w*8+7 of 32 total
// (tiles 0..15 -> Ha cols, 16..31 -> Hb cols). K=128 = 4 k-steps.
// ---------------------------------------------------------------------------
__global__ __launch_bounds__(256) void k1_mfma(
    const float* __restrict__ h, const float* __restrict__ W1,
    const float* __restrict__ b1, float* __restrict__ Ha, float* __restrict__ Hb) {
  const int tid = threadIdx.x;
  const int lane = tid & 63;
  const int wave = tid >> 6;
  const int ln = lane & 15;
  const int quad = lane >> 4;
  const int r0 = blockIdx.x * 16;

  // A-fragments: h[(r0+ln)*128 + ks*32 + quad*8 + 0..7] -> bf16
  BF8 afr[4];
  const float4* h4 = (const float4*)h;
  const int abase = (r0 + ln) * 32 + quad * 2;
#pragma unroll
  for (int ks = 0; ks < 4; ks++)
    afr[ks] = make_bf8(h4[abase + ks * 8], h4[abase + ks * 8 + 1]);

#pragma unroll
  for (int t = 0; t < 8; t++) {
    const int nt = wave * 8 + t;
    const bool isA = (nt < 16);
    const int ncol = (isA ? nt : nt - 16) * 16 + ln;
    const int koff = isA ? 0 : 128;
    f32x4 acc;
    const float seed = isA ? b1[ncol] : 0.f;
    acc[0] = seed; acc[1] = seed; acc[2] = seed; acc[3] = seed;
#pragma unroll
    for (int ks = 0; ks < 4; ks++) {
      const BF8 bf = load_bfrag(W1, koff + ks * 32 + quad * 8, HID, ncol);
      acc = __builtin_amdgcn_mfma_f32_16x16x32_bf16(afr[ks].v, bf.v, acc, 0, 0, 0);
    }
    float* dest = isA ? Ha : Hb;
#pragma unroll
    for (int r = 0; r < 4; r++)
      dest[(size_t)(r0 + quad * 4 + r) * HID + ncol] = acc[r];
  }
}

// ---------------------------------------------------------------------------
// K2 (MFMA): unchanged from R5 (proven).
// ---------------------------------------------------------------------------
__global__ __launch_bounds__(256) void k2_mfma(
    const float* __restrict__ Ha, const float* __restrict__ Hb,
    const float* __restrict__ E, const float* __restrict__ adj,
    const float* __restrict__ W1, float* __restrict__ aggH,
    float* __restrict__ cnt) {
  __shared__ __align__(16) unsigned sEbU[4 * NN * 12];  // 48 KB bf16 E, row stride 24
  __shared__ __align__(16) float sHb[16 * HID];         // 16 KB Hb j-tile
  __shared__ __align__(16) float sAdj[4 * NN];          // 4 KB
  const int tid = threadIdx.x;
  const int lane = tid & 63;
  const int wave = tid >> 6;
  const int n = lane & 15;
  const int quad = lane >> 4;
  const int c0 = wave * 64;
  const int r0 = blockIdx.x * 4;
  const int b = r0 >> 8;

  const float4* Eb4 = (const float4*)(E + (size_t)r0 * NN * EDGE_DIM);
  for (int q = tid; q < 4 * NN * 4; q += 256) {
    const float4 v = Eb4[q];
    const int row = q >> 2;
    const int ku = (q & 3) << 1;
    sEbU[row * 12 + ku] = pack_bf2(v.x, v.y);
    sEbU[row * 12 + ku + 1] = pack_bf2(v.z, v.w);
  }
  for (int idx = tid; idx < 4 * NN; idx += 256)
    sAdj[idx] = adj[(size_t)r0 * NN + idx];

  union { bf16x8 v; unsigned short s[8]; } bfrag[4];
#pragma unroll
  for (int ct = 0; ct < 4; ct++) {
#pragma unroll
    for (int jj = 0; jj < 8; jj++) {
      float w = 0.f;
      if (quad < 2)
        w = W1[(size_t)(2 * NODE_DIM + quad * 8 + jj) * HID + c0 + ct * 16 + n];
      bfrag[ct].s[jj] = (short)f2bf(w);
    }
  }
  float hav[4][4];
#pragma unroll
  for (int i = 0; i < 4; i++)
#pragma unroll
    for (int ct = 0; ct < 4; ct++)
      hav[i][ct] = Ha[(size_t)(r0 + i) * HID + c0 + ct * 16 + n];

  __syncthreads();

  {
    float s = sAdj[wave * NN + lane] + sAdj[wave * NN + lane + 64] +
              sAdj[wave * NN + lane + 128] + sAdj[wave * NN + lane + 192];
    for (int d = 32; d; d >>= 1) s += __shfl_xor(s, d);
    if (lane == 0) cnt[r0 + wave] = s;
  }

  float outp[4][4];
#pragma unroll
  for (int i = 0; i < 4; i++)
#pragma unroll
    for (int ct = 0; ct < 4; ct++) outp[i][ct] = 0.f;

  for (int jt = 0; jt < 16; jt++) {
    const int j0 = jt * 16;
    cp_glds_16(Hb + ((size_t)(b * NN) + j0) * HID, sHb, 16 * HID * 4, tid);
    __syncthreads();
#pragma unroll
    for (int i = 0; i < 4; i++) {
      const bf16x8 af = *(const bf16x8*)((const char*)sEbU +
          (size_t)(i * NN + j0 + n) * 48 + (quad & 1) * 16);
      const float4 adjv = *(const float4*)(sAdj + i * NN + j0 + quad * 4);
#pragma unroll
      for (int ct = 0; ct < 4; ct++) {
        f32x4 cseed;
        cseed[0] = hav[i][ct]; cseed[1] = hav[i][ct];
        cseed[2] = hav[i][ct]; cseed[3] = hav[i][ct];
        f32x4 acc = __builtin_amdgcn_mfma_f32_16x16x32_bf16(
            af, bfrag[ct].v, cseed, 0, 0, 0);
        const int colb = c0 + ct * 16 + n;
#pragma unroll
        for (int r = 0; r < 4; r++) {
          const float hb = sHb[(quad * 4 + r) * HID + colb];
          const float x = fmaxf(acc[r] + hb, 0.f);
          const float a = (r == 0) ? adjv.x : (r == 1) ? adjv.y
                        : (r == 2) ? adjv.z : adjv.w;
          outp[i][ct] = fmaf(a, x, outp[i][ct]);
        }
      }
    }
    __syncthreads();
  }

#pragma unroll
  for (int i = 0; i < 4; i++)
#pragma unroll
    for (int ct = 0; ct < 4; ct++) {
      float v = outp[i][ct];
      v += __shfl_xor(v, 16);
      v += __shfl_xor(v, 32);
      if (quad == 0)
        aggH[(size_t)(r0 + i) * HID + c0 + ct * 16 + n] = v;
    }
}

// ---------------------------------------------------------------------------
// K3 (MFMA chain, 2 barriers): per 16-row block:
//   agg = aggH@W2 + cnt*b2          (N=128: wave w -> n-tiles 2w,2w+1)
//   u   = relu(h@U1a + agg@U1b + c1) (N=256: wave w -> n-tiles 4w..4w+3)
//   out = u@U2 + c2                  (N=128: wave w -> n-tiles 2w,2w+1)
// Inter-stage activations in LDS as bf16, padded rows (stride 144/272 elems)
// for 16B-aligned ds_read_b128 A-frags with <=4-way bank conflicts.
// ---------------------------------------------------------------------------
#define SAGG_LD 144
#define SU_LD 272
__global__ __launch_bounds__(256) void k3_mfma(
    const float* __restrict__ h, const float* __restrict__ aggH,
    const float* __restrict__ cnt, const float* __restrict__ W2,
    const float* __restrict__ b2, const float* __restrict__ U1,
    const float* __restrict__ c1, const float* __restrict__ U2,
    const float* __restrict__ c2, float* __restrict__ out) {
  __shared__ __align__(16) unsigned short sAgg[16 * SAGG_LD];  // ~4.6 KB
  __shared__ __align__(16) unsigned short sU[16 * SU_LD];      // ~8.7 KB
  const int tid = threadIdx.x;
  const int lane = tid & 63;
  const int wave = tid >> 6;
  const int ln = lane & 15;
  const int quad = lane >> 4;
  const int r0 = blockIdx.x * 16;

  // ---- stage 1: agg = aggH @ W2 + cnt*b2 ----
  {
    BF8 afr[8];  // aggH[(r0+ln), ks*32+quad*8 ..], K=256
    const float4* g4 = (const float4*)aggH;
    const int abase = (r0 + ln) * 64 + quad * 2;
#pragma unroll
    for (int ks = 0; ks < 8; ks++)
      afr[ks] = make_bf8(g4[abase + ks * 8], g4[abase + ks * 8 + 1]);
    const float4 cntv = *(const float4*)(cnt + r0 + quad * 4);
#pragma unroll
    for (int t = 0; t < 2; t++) {
      const int ncol = (2 * wave + t) * 16 + ln;
      const float bv = b2[ncol];
      f32x4 acc;
      acc[0] = cntv.x * bv; acc[1] = cntv.y * bv;
      acc[2] = cntv.z * bv; acc[3] = cntv.w * bv;
#pragma unroll
      for (int ks = 0; ks < 8; ks++) {
        const BF8 bf = load_bfrag(W2, ks * 32 + quad * 8, MSG_DIM, ncol);
        acc = __builtin_amdgcn_mfma_f32_16x16x32_bf16(afr[ks].v, bf.v, acc, 0, 0, 0);
      }
#pragma unroll
      for (int r = 0; r < 4; r++)
        sAgg[(quad * 4 + r) * SAGG_LD + ncol] = f2bf(acc[r]);
    }
  }
  __syncthreads();

  // ---- stage 2: u = relu(h@U1[0:128] + agg@U1[128:256] + c1) ----
  {
    BF8 ah[4];  // h[(r0+ln), ks*32+quad*8 ..]
    const float4* h4 = (const float4*)h;
    const int abase = (r0 + ln) * 32 + quad * 2;
#pragma unroll
    for (int ks = 0; ks < 4; ks++)
      ah[ks] = make_bf8(h4[abase + ks * 8], h4[abase + ks * 8 + 1]);
    BF8 ag[4];  // agg frag from LDS (bf16, contiguous 8 elems = 16 B)
#pragma unroll
    for (int ks = 0; ks < 4; ks++)
      ag[ks] = *(const BF8*)&sAgg[ln * SAGG_LD + ks * 32 + quad * 8];
#pragma unroll
    for (int t = 0; t < 4; t++) {
      const int ncol = (4 * wave + t) * 16 + ln;
      const float seed = c1[ncol];
      f32x4 acc;
      acc[0] = seed; acc[1] = seed; acc[2] = seed; acc[3] = seed;
#pragma unroll
      for (int ks = 0; ks < 4; ks++) {
        const BF8 bf = load_bfrag(U1, ks * 32 + quad * 8, HID, ncol);
        acc = __builtin_amdgcn_mfma_f32_16x16x32_bf16(ah[ks].v, bf.v, acc, 0, 0, 0);
      }
#pragma unroll
      for (int ks = 0; ks < 4; ks++) {
        const BF8 bf = load_bfrag(U1, 128 + ks * 32 + quad * 8, HID, ncol);
        acc = __builtin_amdgcn_mfma_f32_16x16x32_bf16(ag[ks].v, bf.v, acc, 0, 0, 0);
      }
#pragma unroll
      for (int r = 0; r < 4; r++)
        sU[(quad * 4 + r) * SU_LD + ncol] = f2bf(fmaxf(acc[r], 0.f));
    }
  }
  __syncthreads();

  // ---- stage 3: out = u @ U2 + c2 ----
  {
    BF8 au[8];
#pragma unroll
    for (int ks = 0; ks < 8; ks++)
      au[ks] = *(const BF8*)&sU[ln * SU_LD + ks * 32 + quad * 8];
#pragma unroll
    for (int t = 0; t < 2; t++) {
      const int ncol = (2 * wave + t) * 16 + ln;
      const float seed = c2[ncol];
      f32x4 acc;
      acc[0] = seed; acc[1] = seed; acc[2] = seed; acc[3] = seed;
#pragma unroll
      for (int ks = 0; ks < 8; ks++) {
        const BF8 bf = load_bfrag(U2, ks * 32 + quad * 8, NODE_DIM, ncol);
        acc = __builtin_amdgcn_mfma_f32_16x16x32_bf16(au[ks].v, bf.v, acc, 0, 0, 0);
      }
#pragma unroll
      for (int r = 0; r < 4; r++)
        out[(size_t)(r0 + quad * 4 + r) * NODE_DIM + ncol] = acc[r];
    }
  }
}

extern "C" void kernel_launch(void* const* d_in, const int* in_sizes, int n_in,
                              void* d_out, int out_size, void* d_ws, size_t ws_size,
                              hipStream_t stream) {
  const float* h   = (const float*)d_in[0];
  const float* adj = (const float*)d_in[1];
  const float* E   = (const float*)d_in[2];
  const float* W1  = (const float*)d_in[3];
  const float* b1  = (const float*)d_in[4];
  const float* W2  = (const float*)d_in[5];
  const float* b2  = (const float*)d_in[6];
  const float* U1  = (const float*)d_in[7];
  const float* c1  = (const float*)d_in[8];
  const float* U2  = (const float*)d_in[9];
  const float* c2  = (const float*)d_in[10];
  float* out = (float*)d_out;

  const size_t ROWS = (size_t)NB * NN;  // 2048
  float* ws   = (float*)d_ws;
  float* Ha   = ws;                      // 2048*256
  float* Hb   = ws + ROWS * HID;         // 2048*256
  float* aggH = ws + 2 * ROWS * HID;     // 2048*256
  float* cnt  = ws + 3 * ROWS * HID;     // 2048

  k1_mfma<<<ROWS / 16, 256, 0, stream>>>(h, W1, b1, Ha, Hb);
  k2_mfma<<<ROWS / 4, 256, 0, stream>>>(Ha, Hb, E, adj, W1, aggH, cnt);
  k3_mfma<<<ROWS / 16, 256, 0, stream>>>(h, aggH, cnt, W2, b2, U1, c1, U2, c2, out);
}

// Round 8
// 136.115 us; speedup vs baseline: 1.6651x; 1.1558x over previous
//
#include <hip/hip_runtime.h>

#define NODE_DIM 128
#define EDGE_DIM 16
#define MSG_DIM 128
#define HID 256
#define NB 8
#define NN 256

typedef short bf16x8 __attribute__((ext_vector_type(8)));
typedef float f32x4 __attribute__((ext_vector_type(4)));

// Async bulk copy global->LDS, 16B/lane (k2 only). lbase wave-uniform.
__device__ __forceinline__ void cp_glds_16(const void* gbase, void* lbase,
                                           int bytes, int tid) {
  const int lane = tid & 63;
  const int wave = tid >> 6;
  for (int off = wave * 1024; off < bytes; off += 4096) {
    const char* g = (const char*)gbase + off + lane * 16;
    char* l = (char*)lbase + off;
    __builtin_amdgcn_global_load_lds(
        (const __attribute__((address_space(1))) void*)g,
        (__attribute__((address_space(3))) void*)l, 16, 0, 0);
  }
}

__device__ __forceinline__ unsigned short f2bf(float f) {
  unsigned u = __float_as_uint(f);
  return (unsigned short)((u + 0x7FFF + ((u >> 16) & 1)) >> 16);
}
__device__ __forceinline__ unsigned pack_bf2(float lo, float hi) {
  unsigned a = __float_as_uint(lo), b = __float_as_uint(hi);
  a = (a + 0x7FFF + ((a >> 16) & 1)) >> 16;
  b = (b + 0x7FFF + ((b >> 16) & 1)) & 0xFFFF0000u;
  return a | b;
}

union BF8 { bf16x8 v; unsigned u[4]; unsigned short s[8]; };

__device__ __forceinline__ BF8 make_bf8(float4 a, float4 b) {
  BF8 r;
  r.u[0] = pack_bf2(a.x, a.y); r.u[1] = pack_bf2(a.z, a.w);
  r.u[2] = pack_bf2(b.x, b.y); r.u[3] = pack_bf2(b.z, b.w);
  return r;
}

// Packed-fragment sizes (shorts). Frag (nt,ks): 64 lanes x 8 bf16 (16B/lane).
// PW1: nt 0..15, ks 0..8 (272 rows zero-padded to 288). Others: ks 0..7.
#define PW1_SHORTS (16 * 9 * 64 * 8)
#define PW2_SHORTS (8 * 8 * 64 * 8)
#define PU1_SHORTS (16 * 8 * 64 * 8)
#define PU2_SHORTS (8 * 8 * 64 * 8)

// ---------------------------------------------------------------------------
// kW: repack W1/W2/U1/U2 fp32 -> bf16 B-fragment order.
// frag-lane gl -> value j: W[(ks*32 + quad*8 + j)*N + nt*16 + ln].
// ---------------------------------------------------------------------------
__global__ __launch_bounds__(256) void kw_pack(
    const float* __restrict__ W1, const float* __restrict__ W2,
    const float* __restrict__ U1, const float* __restrict__ U2,
    unsigned short* __restrict__ P) {
  const int gl = blockIdx.x * 256 + threadIdx.x;  // 25600 frag-lanes total
  const float* W; unsigned short* dst; int nt, ks, lane, N, K;
  int i = gl;
  if (i < 16 * 9 * 64) {
    W = W1; dst = P; nt = i / (9 * 64); ks = (i / 64) % 9; lane = i & 63;
    N = HID; K = 272;
  } else if ((i -= 16 * 9 * 64) < 8 * 8 * 64) {
    W = W2; dst = P + PW1_SHORTS; nt = i / (8 * 64); ks = (i / 64) % 8;
    lane = i & 63; N = MSG_DIM; K = 256;
  } else if ((i -= 8 * 8 * 64) < 16 * 8 * 64) {
    W = U1; dst = P + PW1_SHORTS + PW2_SHORTS; nt = i / (8 * 64);
    ks = (i / 64) % 8; lane = i & 63; N = HID; K = 256;
  } else if ((i -= 16 * 8 * 64) < 8 * 8 * 64) {
    W = U2; dst = P + PW1_SHORTS + PW2_SHORTS + PU1_SHORTS; nt = i / (8 * 64);
    ks = (i / 64) % 8; lane = i & 63; N = NODE_DIM; K = 256;
  } else {
    return;
  }
  const int quad = lane >> 4, ln = lane & 15;
  float v[8];
#pragma unroll
  for (int j = 0; j < 8; j++) {
    const int row = ks * 32 + quad * 8 + j;
    v[j] = (row < K) ? W[(size_t)row * N + nt * 16 + ln] : 0.f;
  }
  BF8 r;
#pragma unroll
  for (int t = 0; t < 4; t++) r.u[t] = pack_bf2(v[2 * t], v[2 * t + 1]);
  *(BF8*)(dst + (size_t)((nt * ((W == W1) ? 9 : 8) + ks) * 64 + lane) * 8) = r;
}

// ---------------------------------------------------------------------------
// K1 (MFMA, no barriers, packed B): [Ha|Hb] = h @ W1[0:256,:] (+b1 for Ha).
// Grid 256 = 128 rowBlks x 2 col-halves; each col-half covers n-tiles
// nbase..nbase+7 (nbase = 0 or 8); wave -> 2 n-tiles (wave*2+t).
// Each nt computes acc_a (ks0..3 -> Ha) and acc_b (ks4..7 -> Hb).
// ---------------------------------------------------------------------------
__global__ __launch_bounds__(256) void k1_mfma(
    const float* __restrict__ h, const unsigned short* __restrict__ PW1,
    const float* __restrict__ b1, float* __restrict__ Ha, float* __restrict__ Hb) {
  const int tid = threadIdx.x;
  const int lane = tid & 63;
  const int wave = tid >> 6;
  const int ln = lane & 15;
  const int quad = lane >> 4;
  const int r0 = (blockIdx.x >> 1) * 16;
  const int nbase = (blockIdx.x & 1) * 8;  // n-tile base (16 tiles total)

  BF8 afr[4];  // h[(r0+ln), ks*32+quad*8 ..] bf16
  const float4* h4 = (const float4*)h;
  const int abase = (r0 + ln) * 32 + quad * 2;
#pragma unroll
  for (int ks = 0; ks < 4; ks++)
    afr[ks] = make_bf8(h4[abase + ks * 8], h4[abase + ks * 8 + 1]);

#pragma unroll
  for (int t = 0; t < 2; t++) {
    const int nt = nbase + wave * 2 + t;  // 0..15
    const int ncol = nt * 16 + ln;
    const float seed = b1[ncol];
    f32x4 acc_a, acc_b;
    acc_a[0] = seed; acc_a[1] = seed; acc_a[2] = seed; acc_a[3] = seed;
    acc_b[0] = 0.f; acc_b[1] = 0.f; acc_b[2] = 0.f; acc_b[3] = 0.f;
#pragma unroll
    for (int ks = 0; ks < 4; ks++) {
      const BF8 bfa = *(const BF8*)(PW1 + (size_t)((nt * 9 + ks) * 64 + lane) * 8);
      const BF8 bfb = *(const BF8*)(PW1 + (size_t)((nt * 9 + ks + 4) * 64 + lane) * 8);
      acc_a = __builtin_amdgcn_mfma_f32_16x16x32_bf16(afr[ks].v, bfa.v, acc_a, 0, 0, 0);
      acc_b = __builtin_amdgcn_mfma_f32_16x16x32_bf16(afr[ks].v, bfb.v, acc_b, 0, 0, 0);
    }
#pragma unroll
    for (int r = 0; r < 4; r++) {
      Ha[(size_t)(r0 + quad * 4 + r) * HID + ncol] = acc_a[r];
      Hb[(size_t)(r0 + quad * 4 + r) * HID + ncol] = acc_b[r];
    }
  }
}

// ---------------------------------------------------------------------------
// K2 (MFMA): byte-identical to R5/R6 (control).
// ---------------------------------------------------------------------------
__global__ __launch_bounds__(256) void k2_mfma(
    const float* __restrict__ Ha, const float* __restrict__ Hb,
    const float* __restrict__ E, const float* __restrict__ adj,
    const float* __restrict__ W1, float* __restrict__ aggH,
    float* __restrict__ cnt) {
  __shared__ __align__(16) unsigned sEbU[4 * NN * 12];
  __shared__ __align__(16) float sHb[16 * HID];
  __shared__ __align__(16) float sAdj[4 * NN];
  const int tid = threadIdx.x;
  const int lane = tid & 63;
  const int wave = tid >> 6;
  const int n = lane & 15;
  const int quad = lane >> 4;
  const int c0 = wave * 64;
  const int r0 = blockIdx.x * 4;
  const int b = r0 >> 8;

  const float4* Eb4 = (const float4*)(E + (size_t)r0 * NN * EDGE_DIM);
  for (int q = tid; q < 4 * NN * 4; q += 256) {
    const float4 v = Eb4[q];
    const int row = q >> 2;
    const int ku = (q & 3) << 1;
    sEbU[row * 12 + ku] = pack_bf2(v.x, v.y);
    sEbU[row * 12 + ku + 1] = pack_bf2(v.z, v.w);
  }
  for (int idx = tid; idx < 4 * NN; idx += 256)
    sAdj[idx] = adj[(size_t)r0 * NN + idx];

  union { bf16x8 v; unsigned short s[8]; } bfrag[4];
#pragma unroll
  for (int ct = 0; ct < 4; ct++) {
#pragma unroll
    for (int jj = 0; jj < 8; jj++) {
      float w = 0.f;
      if (quad < 2)
        w = W1[(size_t)(2 * NODE_DIM + quad * 8 + jj) * HID + c0 + ct * 16 + n];
      bfrag[ct].s[jj] = (short)f2bf(w);
    }
  }
  float hav[4][4];
#pragma unroll
  for (int i = 0; i < 4; i++)
#pragma unroll
    for (int ct = 0; ct < 4; ct++)
      hav[i][ct] = Ha[(size_t)(r0 + i) * HID + c0 + ct * 16 + n];

  __syncthreads();

  {
    float s = sAdj[wave * NN + lane] + sAdj[wave * NN + lane + 64] +
              sAdj[wave * NN + lane + 128] + sAdj[wave * NN + lane + 192];
    for (int d = 32; d; d >>= 1) s += __shfl_xor(s, d);
    if (lane == 0) cnt[r0 + wave] = s;
  }

  float outp[4][4];
#pragma unroll
  for (int i = 0; i < 4; i++)
#pragma unroll
    for (int ct = 0; ct < 4; ct++) outp[i][ct] = 0.f;

  for (int jt = 0; jt < 16; jt++) {
    const int j0 = jt * 16;
    cp_glds_16(Hb + ((size_t)(b * NN) + j0) * HID, sHb, 16 * HID * 4, tid);
    __syncthreads();
#pragma unroll
    for (int i = 0; i < 4; i++) {
      const bf16x8 af = *(const bf16x8*)((const char*)sEbU +
          (size_t)(i * NN + j0 + n) * 48 + (quad & 1) * 16);
      const float4 adjv = *(const float4*)(sAdj + i * NN + j0 + quad * 4);
#pragma unroll
      for (int ct = 0; ct < 4; ct++) {
        f32x4 cseed;
        cseed[0] = hav[i][ct]; cseed[1] = hav[i][ct];
        cseed[2] = hav[i][ct]; cseed[3] = hav[i][ct];
        f32x4 acc = __builtin_amdgcn_mfma_f32_16x16x32_bf16(
            af, bfrag[ct].v, cseed, 0, 0, 0);
        const int colb = c0 + ct * 16 + n;
#pragma unroll
        for (int r = 0; r < 4; r++) {
          const float hb = sHb[(quad * 4 + r) * HID + colb];
          const float x = fmaxf(acc[r] + hb, 0.f);
          const float a = (r == 0) ? adjv.x : (r == 1) ? adjv.y
                        : (r == 2) ? adjv.z : adjv.w;
          outp[i][ct] = fmaf(a, x, outp[i][ct]);
        }
      }
    }
    __syncthreads();
  }

#pragma unroll
  for (int i = 0; i < 4; i++)
#pragma unroll
    for (int ct = 0; ct < 4; ct++) {
      float v = outp[i][ct];
      v += __shfl_xor(v, 16);
      v += __shfl_xor(v, 32);
      if (quad == 0)
        aggH[(size_t)(r0 + i) * HID + c0 + ct * 16 + n] = v;
    }
}

// ---------------------------------------------------------------------------
// K3 (MFMA chain, packed B, 2 barriers): per 16-row block (128 blocks):
//   agg = aggH@W2 + cnt*b2; u = relu(h@U1a + agg@U1b + c1); out = u@U2 + c2.
// Inter-stage activations in LDS bf16, padded (LD 136 / 264 shorts).
// ---------------------------------------------------------------------------
#define SAGG_LD 136
#define SU_LD 264
__global__ __launch_bounds__(256) void k3_mfma(
    const float* __restrict__ h, const float* __restrict__ aggH,
    const float* __restrict__ cnt, const unsigned short* __restrict__ PW2,
    const float* __restrict__ b2, const unsigned short* __restrict__ PU1,
    const float* __restrict__ c1, const unsigned short* __restrict__ PU2,
    const float* __restrict__ c2, float* __restrict__ out) {
  __shared__ __align__(16) unsigned short sAgg[16 * SAGG_LD];
  __shared__ __align__(16) unsigned short sU[16 * SU_LD];
  const int tid = threadIdx.x;
  const int lane = tid & 63;
  const int wave = tid >> 6;
  const int ln = lane & 15;
  const int quad = lane >> 4;
  const int r0 = blockIdx.x * 16;

  // ---- stage 1: agg = aggH @ W2 + cnt*b2 (N=128: wave -> nt 2w,2w+1) ----
  {
    BF8 afr[8];
    const float4* g4 = (const float4*)aggH;
    const int abase = (r0 + ln) * 64 + quad * 2;
#pragma unroll
    for (int ks = 0; ks < 8; ks++)
      afr[ks] = make_bf8(g4[abase + ks * 8], g4[abase + ks * 8 + 1]);
    const float4 cntv = *(const float4*)(cnt + r0 + quad * 4);
#pragma unroll
    for (int t = 0; t < 2; t++) {
      const int nt = 2 * wave + t;
      const int ncol = nt * 16 + ln;
      const float bv = b2[ncol];
      f32x4 acc;
      acc[0] = cntv.x * bv; acc[1] = cntv.y * bv;
      acc[2] = cntv.z * bv; acc[3] = cntv.w * bv;
#pragma unroll
      for (int ks = 0; ks < 8; ks++) {
        const BF8 bf = *(const BF8*)(PW2 + (size_t)((nt * 8 + ks) * 64 + lane) * 8);
        acc = __builtin_amdgcn_mfma_f32_16x16x32_bf16(afr[ks].v, bf.v, acc, 0, 0, 0);
      }
#pragma unroll
      for (int r = 0; r < 4; r++)
        sAgg[(quad * 4 + r) * SAGG_LD + ncol] = f2bf(acc[r]);
    }
  }
  __syncthreads();

  // ---- stage 2: u = relu(h@U1[0:128] + agg@U1[128:256] + c1) ----
  {
    BF8 ah[4];
    const float4* h4 = (const float4*)h;
    const int abase = (r0 + ln) * 32 + quad * 2;
#pragma unroll
    for (int ks = 0; ks < 4; ks++)
      ah[ks] = make_bf8(h4[abase + ks * 8], h4[abase + ks * 8 + 1]);
    BF8 ag[4];
#pragma unroll
    for (int ks = 0; ks < 4; ks++)
      ag[ks] = *(const BF8*)&sAgg[ln * SAGG_LD + ks * 32 + quad * 8];
#pragma unroll
    for (int t = 0; t < 4; t++) {
      const int nt = 4 * wave + t;
      const int ncol = nt * 16 + ln;
      const float seed = c1[ncol];
      f32x4 acc;
      acc[0] = seed; acc[1] = seed; acc[2] = seed; acc[3] = seed;
#pragma unroll
      for (int ks = 0; ks < 4; ks++) {
        const BF8 bf = *(const BF8*)(PU1 + (size_t)((nt * 8 + ks) * 64 + lane) * 8);
        acc = __builtin_amdgcn_mfma_f32_16x16x32_bf16(ah[ks].v, bf.v, acc, 0, 0, 0);
      }
#pragma unroll
      for (int ks = 0; ks < 4; ks++) {
        const BF8 bf = *(const BF8*)(PU1 + (size_t)((nt * 8 + ks + 4) * 64 + lane) * 8);
        acc = __builtin_amdgcn_mfma_f32_16x16x32_bf16(ag[ks].v, bf.v, acc, 0, 0, 0);
      }
#pragma unroll
      for (int r = 0; r < 4; r++)
        sU[(quad * 4 + r) * SU_LD + ncol] = f2bf(fmaxf(acc[r], 0.f));
    }
  }
  __syncthreads();

  // ---- stage 3: out = u @ U2 + c2 (N=128: wave -> nt 2w,2w+1) ----
  {
    BF8 au[8];
#pragma unroll
    for (int ks = 0; ks < 8; ks++)
      au[ks] = *(const BF8*)&sU[ln * SU_LD + ks * 32 + quad * 8];
#pragma unroll
    for (int t = 0; t < 2; t++) {
      const int nt = 2 * wave + t;
      const int ncol = nt * 16 + ln;
      const float seed = c2[ncol];
      f32x4 acc;
      acc[0] = seed; acc[1] = seed; acc[2] = seed; acc[3] = seed;
#pragma unroll
      for (int ks = 0; ks < 8; ks++) {
        const BF8 bf = *(const BF8*)(PU2 + (size_t)((nt * 8 + ks) * 64 + lane) * 8);
        acc = __builtin_amdgcn_mfma_f32_16x16x32_bf16(au[ks].v, bf.v, acc, 0, 0, 0);
      }
#pragma unroll
      for (int r = 0; r < 4; r++)
        out[(size_t)(r0 + quad * 4 + r) * NODE_DIM + ncol] = acc[r];
    }
  }
}

extern "C" void kernel_launch(void* const* d_in, const int* in_sizes, int n_in,
                              void* d_out, int out_size, void* d_ws, size_t ws_size,
                              hipStream_t stream) {
  const float* h   = (const float*)d_in[0];
  const float* adj = (const float*)d_in[1];
  const float* E   = (const float*)d_in[2];
  const float* W1  = (const float*)d_in[3];
  const float* b1  = (const float*)d_in[4];
  const float* W2  = (const float*)d_in[5];
  const float* b2  = (const float*)d_in[6];
  const float* U1  = (const float*)d_in[7];
  const float* c1  = (const float*)d_in[8];
  const float* U2  = (const float*)d_in[9];
  const float* c2  = (const float*)d_in[10];
  float* out = (float*)d_out;

  const size_t ROWS = (size_t)NB * NN;  // 2048
  float* ws   = (float*)d_ws;
  float* Ha   = ws;                      // 2048*256
  float* Hb   = ws + ROWS * HID;         // 2048*256
  float* aggH = ws + 2 * ROWS * HID;     // 2048*256
  float* cnt  = ws + 3 * ROWS * HID;     // 2048
  unsigned short* P = (unsigned short*)(cnt + ROWS);  // packed weights, 16B-aligned
  unsigned short* PW1 = P;
  unsigned short* PW2 = P + PW1_SHORTS;
  unsigned short* PU1 = PW2 + PW2_SHORTS;
  unsigned short* PU2 = PU1 + PU1_SHORTS;

  kw_pack<<<100, 256, 0, stream>>>(W1, W2, U1, U2, P);
  k1_mfma<<<256, 256, 0, stream>>>(h, PW1, b1, Ha, Hb);
  k2_mfma<<<ROWS / 4, 256, 0, stream>>>(Ha, Hb, E, adj, W1, aggH, cnt);
  k3_mfma<<<ROWS / 16, 256, 0, stream>>>(h, aggH, cnt, PW2, b2, PU1, c1, PU2, c2, out);
}